// Round 1
// baseline (36.696 us; speedup 1.0000x reference)
//
#include <hip/hip_runtime.h>
#include <math.h>

// TripletLoss: B=16384 rows, D=1024 fp32.
// dp=||a-p||, dn=||a-n||, loss=softplus(dp-dn), out = mean(loss).
// Memory-bound: 192 MiB read once -> ~32us floor at 6.3 TB/s.

#define B_ROWS 16384
#define D_DIM  1024
#define NBLOCKS 2048   // 4 waves/block -> 8192 waves, 2 rows per wave

__global__ __launch_bounds__(256) void triplet_partial_kernel(
    const float* __restrict__ a,
    const float* __restrict__ p,
    const float* __restrict__ n,
    float* __restrict__ partial)
{
    const int wave = threadIdx.x >> 6;   // 0..3
    const int lane = threadIdx.x & 63;
    const int globalWave = blockIdx.x * 4 + wave;
    const int totalWaves = gridDim.x * 4;

    float acc = 0.0f;  // per-wave loss accumulator (lane 0 only meaningful)

    for (int row = globalWave; row < B_ROWS; row += totalWaves) {
        const float4* a4 = (const float4*)(a + (size_t)row * D_DIM);
        const float4* p4 = (const float4*)(p + (size_t)row * D_DIM);
        const float4* n4 = (const float4*)(n + (size_t)row * D_DIM);
        float sp = 0.0f, sn = 0.0f;
        #pragma unroll
        for (int k = 0; k < 4; ++k) {
            const int idx = lane + 64 * k;   // coalesced: 64 lanes x 16B contiguous
            float4 av = a4[idx];
            float4 pv = p4[idx];
            float4 nv = n4[idx];
            float d0 = av.x - pv.x, d1 = av.y - pv.y,
                  d2 = av.z - pv.z, d3 = av.w - pv.w;
            sp += d0*d0 + d1*d1 + d2*d2 + d3*d3;
            d0 = av.x - nv.x; d1 = av.y - nv.y;
            d2 = av.z - nv.z; d3 = av.w - nv.w;
            sn += d0*d0 + d1*d1 + d2*d2 + d3*d3;
        }
        // 64-lane butterfly reduce (wave = 64 on CDNA)
        #pragma unroll
        for (int off = 32; off > 0; off >>= 1) {
            sp += __shfl_xor(sp, off, 64);
            sn += __shfl_xor(sn, off, 64);
        }
        if (lane == 0) {
            float dp = sqrtf(sp);
            float dn = sqrtf(sn);
            float x  = dp - dn;
            // stable softplus: logaddexp(0,x) = max(x,0) + log1p(exp(-|x|))
            acc += fmaxf(x, 0.0f) + log1pf(expf(-fabsf(x)));
        }
    }

    __shared__ float smem[4];
    if (lane == 0) smem[wave] = acc;
    __syncthreads();
    if (threadIdx.x == 0)
        partial[blockIdx.x] = smem[0] + smem[1] + smem[2] + smem[3];
}

__global__ __launch_bounds__(256) void triplet_final_kernel(
    const float* __restrict__ partial, float* __restrict__ out)
{
    const int wave = threadIdx.x >> 6;
    const int lane = threadIdx.x & 63;
    float acc = 0.0f;
    for (int i = threadIdx.x; i < NBLOCKS; i += 256) acc += partial[i];
    #pragma unroll
    for (int off = 32; off > 0; off >>= 1) acc += __shfl_xor(acc, off, 64);
    __shared__ float smem[4];
    if (lane == 0) smem[wave] = acc;
    __syncthreads();
    if (threadIdx.x == 0)
        out[0] = (smem[0] + smem[1] + smem[2] + smem[3]) * (1.0f / (float)B_ROWS);
}

extern "C" void kernel_launch(void* const* d_in, const int* in_sizes, int n_in,
                              void* d_out, int out_size, void* d_ws, size_t ws_size,
                              hipStream_t stream) {
    const float* anchor   = (const float*)d_in[0];
    const float* positive = (const float*)d_in[1];
    const float* negative = (const float*)d_in[2];
    float* out = (float*)d_out;
    float* partials = (float*)d_ws;   // NBLOCKS floats = 8 KB scratch

    triplet_partial_kernel<<<NBLOCKS, 256, 0, stream>>>(anchor, positive, negative, partials);
    triplet_final_kernel<<<1, 256, 0, stream>>>(partials, out);
}